// Round 3
// baseline (266.295 us; speedup 1.0000x reference)
//
#include <hip/hip_runtime.h>
#include <math.h>

// Problem constants (from reference): B=8, C=512, L=4096, fp32.
#define C_CH   512
#define TOPK   256               // C * (1 - EXCHANGE_RATIO)
#define B_N    8
#define L_LEN  4096
#define L4     (L_LEN / 4)       // 1024 float4 per channel row (16 KB)
#define ROWS_T (B_N * C_CH)      // 4096 rows per output tensor
#define NJOBS  (2 * ROWS_T)      // 8192 independent row-copy jobs (y1 then y2)
#define NBLK   2048              // 8 blocks/CU; each block does 4 jobs

// Native vector type for nontemporal builtins (HIP float4 wrapper is rejected).
typedef float nf4 __attribute__((ext_vector_type(4)));

// Build per-output-channel source maps.
// map1[c]: source for y1 channel c. s < C_CH -> x1 channel s; else x2 channel s-C_CH.
// map2[c]: source for y2 channel c. s < C_CH -> x2 channel s; else x1 channel s-C_CH.
// Channel c is "top" iff rank of |bn[c]| < TOPK (ties -> lower index first, matching
// jax.lax.top_k). Non-top channels are exchanged, aligned by ascending-index position.
__global__ __launch_bounds__(C_CH) void build_maps(
        const float* __restrict__ bn1,
        const float* __restrict__ bn2,
        int* __restrict__ map1,
        int* __restrict__ map2) {
    __shared__ float2 a12[C_CH];
    __shared__ int nt1[C_CH - TOPK], nt2[C_CH - TOPK];
    __shared__ int wsum1[8], wsum2[8];
    const int t = threadIdx.x;
    const float v1 = fabsf(bn1[t]);
    const float v2 = fabsf(bn2[t]);
    a12[t] = make_float2(v1, v2);
    __syncthreads();

    // Rank among |bn| values (descending, ties by lower index).
    int r1 = 0, r2 = 0;
#pragma unroll 8
    for (int j = 0; j < C_CH; ++j) {
        const float2 bj = a12[j];
        r1 += (bj.x > v1) || (bj.x == v1 && j < t);
        r2 += (bj.y > v2) || (bj.y == v2 && j < t);
    }
    const bool non1 = (r1 >= TOPK);
    const bool non2 = (r2 >= TOPK);

    // Ballot-based prefix count of non-top flags (position in ascending index order).
    const unsigned long long m1 = __ballot(non1);
    const unsigned long long m2 = __ballot(non2);
    const int lane = t & 63, w = t >> 6;
    const unsigned long long below = (1ULL << lane) - 1ULL;
    const int lp1 = __popcll(m1 & below);
    const int lp2 = __popcll(m2 & below);
    if (lane == 0) { wsum1[w] = __popcll(m1); wsum2[w] = __popcll(m2); }
    __syncthreads();
    int base1 = 0, base2 = 0;
#pragma unroll
    for (int i = 0; i < 8; ++i) {
        base1 += (i < w) ? wsum1[i] : 0;
        base2 += (i < w) ? wsum2[i] : 0;
    }
    const int p1 = base1 + lp1;
    const int p2 = base2 + lp2;
    if (non1) nt1[p1] = t;
    if (non2) nt2[p2] = t;
    __syncthreads();

    map1[t] = non1 ? (C_CH + nt2[p1]) : t;
    map2[t] = non2 ? (C_CH + nt1[p2]) : t;
}

// v3: persistent pipelined row-copy. 8192 jobs (one 16 KB output row each),
// 2048 blocks x 4 jobs. Four DISJOINT register quads (no WAR on store-data regs
// -> no store-completion waits) scheduled L0 L1 S0 L2 S1 L3 S2 S3, so new loads
// keep issuing while earlier stores drain. This removes the read-phase /
// store-drain alternation of the one-shot version (which sat at 31% HBM peak
// with all pipes idle). Stores are nontemporal (outputs never re-read; keeps
// inputs LLC-resident -> FETCH_SIZE ~ half of logical reads).
struct Job { const float4* __restrict__ src; float4* __restrict__ dst; };

__device__ __forceinline__ Job job_addr(int job,
        const float4* __restrict__ x1, const float4* __restrict__ x2,
        const int* __restrict__ map1, const int* __restrict__ map2,
        float4* __restrict__ y1, float4* __restrict__ y2) {
    const int rr = job & (ROWS_T - 1);       // row within tensor
    const int c = rr & (C_CH - 1);
    const int b = rr >> 9;
    const bool second = job >= ROWS_T;       // y2 half
    const int m = second ? map2[c] : map1[c];            // uniform -> s_load
    const float4* base = second ? ((m < C_CH) ? x2 : x1)
                                : ((m < C_CH) ? x1 : x2);
    Job j;
    j.src = base + ((size_t)((b << 9) | (m & (C_CH - 1))) << 10);
    j.dst = (second ? y2 : y1) + ((size_t)rr << 10);
    return j;
}

__global__ __launch_bounds__(256) void exchange_copy(
        const float4* __restrict__ x1,
        const float4* __restrict__ x2,
        const int* __restrict__ map1,
        const int* __restrict__ map2,
        float4* __restrict__ y1,
        float4* __restrict__ y2) {
    const int t = threadIdx.x;
    const int blk = blockIdx.x;

    // Jobs: blk, blk+NBLK, blk+2*NBLK, blk+3*NBLK. Consecutive blocks write
    // consecutive rows -> machine-wide coalesced write stream each stage.
    const Job j0 = job_addr(blk,            x1, x2, map1, map2, y1, y2);
    const Job j1 = job_addr(blk + NBLK,     x1, x2, map1, map2, y1, y2);
    const Job j2 = job_addr(blk + 2 * NBLK, x1, x2, map1, map2, y1, y2);
    const Job j3 = job_addr(blk + 3 * NBLK, x1, x2, map1, map2, y1, y2);

    float4 r0[4], r1[4], r2[4], r3[4];

    // L0 L1
#pragma unroll
    for (int k = 0; k < 4; ++k) r0[k] = j0.src[t + 256 * k];
#pragma unroll
    for (int k = 0; k < 4; ++k) r1[k] = j1.src[t + 256 * k];
    // S0
#pragma unroll
    for (int k = 0; k < 4; ++k)
        __builtin_nontemporal_store(*(const nf4*)&r0[k], (nf4*)j0.dst + t + 256 * k);
    // L2
#pragma unroll
    for (int k = 0; k < 4; ++k) r2[k] = j2.src[t + 256 * k];
    // S1
#pragma unroll
    for (int k = 0; k < 4; ++k)
        __builtin_nontemporal_store(*(const nf4*)&r1[k], (nf4*)j1.dst + t + 256 * k);
    // L3
#pragma unroll
    for (int k = 0; k < 4; ++k) r3[k] = j3.src[t + 256 * k];
    // S2
#pragma unroll
    for (int k = 0; k < 4; ++k)
        __builtin_nontemporal_store(*(const nf4*)&r2[k], (nf4*)j2.dst + t + 256 * k);
    // S3
#pragma unroll
    for (int k = 0; k < 4; ++k)
        __builtin_nontemporal_store(*(const nf4*)&r3[k], (nf4*)j3.dst + t + 256 * k);
}

extern "C" void kernel_launch(void* const* d_in, const int* in_sizes, int n_in,
                              void* d_out, int out_size, void* d_ws, size_t ws_size,
                              hipStream_t stream) {
    const float* x1  = (const float*)d_in[0];
    const float* x2  = (const float*)d_in[1];
    const float* bn1 = (const float*)d_in[2];
    const float* bn2 = (const float*)d_in[3];

    float* y1 = (float*)d_out;                         // first B*C*L floats
    float* y2 = (float*)d_out + (B_N * C_CH * L_LEN);  // second output

    int* map1 = (int*)d_ws;
    int* map2 = map1 + C_CH;

    build_maps<<<1, C_CH, 0, stream>>>(bn1, bn2, map1, map2);

    exchange_copy<<<NBLK, 256, 0, stream>>>(
        (const float4*)x1, (const float4*)x2, map1, map2,
        (float4*)y1, (float4*)y2);
}